// Round 1
// 552.636 us; speedup vs baseline: 2.8956x; 2.8956x over previous
//
#include <hip/hip_runtime.h>
#include <hip/hip_bf16.h>

#define SEQ  200
#define DIM  512
#define NH   8
#define DF   64
#define SPAD 256
#define NEG  -1.0e30f

typedef __bf16 bf16x8 __attribute__((ext_vector_type(8)));
typedef float  f32x4  __attribute__((ext_vector_type(4)));

// ---------------------------------------------------------------------------
// Per-tensor dtype detection (512 u16 words). flag=1 -> f32.
// ---------------------------------------------------------------------------
__global__ void detect_kernel(const unsigned short* __restrict__ src,
                              int* __restrict__ flag)
{
    __shared__ int cnt;
    if (threadIdx.x == 0) cnt = 0;
    __syncthreads();
    int ok = 0;
#pragma unroll
    for (int i = 0; i < 2; ++i) {
        const unsigned short u = src[threadIdx.x * 2 + i];
        const float f = __uint_as_float(((unsigned int)u) << 16);
        const float a = fabsf(f);
        ok += (f == 0.0f) || (a >= 6.0e-5f && a <= 64.0f);
    }
    atomicAdd(&cnt, ok);
    __syncthreads();
    if (threadIdx.x == 0) flag[0] = (cnt < 448) ? 1 : 0;
}

// ---------------------------------------------------------------------------
// Canonicalize a tensor to bf16 according to its own flag.
// ---------------------------------------------------------------------------
__global__ void cvt_kernel(const void* __restrict__ src,
                           __bf16* __restrict__ dst, long n8,
                           const int* __restrict__ flag)
{
    const int f32mode = flag[0];
    long i = (long)blockIdx.x * blockDim.x + threadIdx.x;
    const long stride = (long)gridDim.x * blockDim.x;
    if (f32mode) {
        const f32x4* s = (const f32x4*)src;
        for (; i < n8; i += stride) {
            const f32x4 a = s[2 * i], b = s[2 * i + 1];
            bf16x8 o;
            o[0] = (__bf16)a[0]; o[1] = (__bf16)a[1];
            o[2] = (__bf16)a[2]; o[3] = (__bf16)a[3];
            o[4] = (__bf16)b[0]; o[5] = (__bf16)b[1];
            o[6] = (__bf16)b[2]; o[7] = (__bf16)b[3];
            ((bf16x8*)dst)[i] = o;
        }
    } else {
        const bf16x8* s = (const bf16x8*)src;
        for (; i < n8; i += stride) ((bf16x8*)dst)[i] = s[i];
    }
}

// ---------------------------------------------------------------------------
// GEMM: C = A[m_off.., K] @ Bt[N,K]^T + bias[N]; fp32 accum.
// MODE 0: C row-major [M,N]; MODE 1: C->[b,H,S,DF]; MODE 2: C->[b,H,DF,SPAD].
// ---------------------------------------------------------------------------
template <int MODE, int USE_FLAG, typename OutT>
__global__ __launch_bounds__(256, 2)
void gemm_bt_kernel(const void* __restrict__ Araw, long m_off,
                    const __bf16* __restrict__ Bt,
                    const __bf16* __restrict__ bias,
                    OutT* __restrict__ C,
                    int M, int N, int K,
                    const int* __restrict__ flag)
{
    __shared__ __align__(16) __bf16 lA[128 * 32];
    __shared__ __align__(16) __bf16 lB[128 * 32];

    const int af32 = USE_FLAG ? flag[0] : 0;
    const __bf16* A16 = (const __bf16*)Araw;
    const float*  A32 = (const float*)Araw;

    const int tid  = threadIdx.x;
    const int m0   = blockIdx.x * 128;
    const int n0   = blockIdx.y * 128;
    const int w    = tid >> 6;
    const int lane = tid & 63;
    const int lr   = lane & 15, quad = lane >> 4;
    const int wm   = (w >> 1) * 64, wn = (w & 1) * 64;

    f32x4 acc[4][4] = {};

    for (int k0 = 0; k0 < K; k0 += 32) {
        bf16x8 ra[2]; uint4 rb[2];
#pragma unroll
        for (int p = 0; p < 2; ++p) {
            const int e = (p * 256 + tid) * 8;
            const int row = e >> 5, col = e & 31;
            const size_t aoff = (size_t)(m_off + m0 + row) * K + (k0 + col);
            if (af32) {
                const f32x4 fa = *(const f32x4*)(A32 + aoff);
                const f32x4 fb = *(const f32x4*)(A32 + aoff + 4);
                bf16x8 o;
                o[0] = (__bf16)fa[0]; o[1] = (__bf16)fa[1];
                o[2] = (__bf16)fa[2]; o[3] = (__bf16)fa[3];
                o[4] = (__bf16)fb[0]; o[5] = (__bf16)fb[1];
                o[6] = (__bf16)fb[2]; o[7] = (__bf16)fb[3];
                ra[p] = o;
            } else {
                ra[p] = *(const bf16x8*)(A16 + aoff);
            }
            rb[p] = *(const uint4*)(Bt + (size_t)(n0 + row) * K + (k0 + col));
        }
        __syncthreads();
#pragma unroll
        for (int p = 0; p < 2; ++p) {
            const int e = (p * 256 + tid) * 8;
            *(bf16x8*)&lA[e] = ra[p];
            *(uint4*)&lB[e]  = rb[p];
        }
        __syncthreads();

        bf16x8 af[4], bfr[4];
#pragma unroll
        for (int mi = 0; mi < 4; ++mi)
            af[mi] = *(const bf16x8*)&lA[(wm + mi * 16 + lr) * 32 + quad * 8];
#pragma unroll
        for (int ni = 0; ni < 4; ++ni)
            bfr[ni] = *(const bf16x8*)&lB[(wn + ni * 16 + lr) * 32 + quad * 8];
#pragma unroll
        for (int mi = 0; mi < 4; ++mi)
#pragma unroll
            for (int ni = 0; ni < 4; ++ni)
                acc[mi][ni] = __builtin_amdgcn_mfma_f32_16x16x32_bf16(
                    af[mi], bfr[ni], acc[mi][ni], 0, 0, 0);
    }

    // C/D layout: col=lane&15, row=quad*4+r  [diag1-verified on-device]
#pragma unroll
    for (int ni = 0; ni < 4; ++ni) {
        const int col = n0 + wn + ni * 16 + lr;
        const float bb = (float)bias[col];
#pragma unroll
        for (int mi = 0; mi < 4; ++mi) {
#pragma unroll
            for (int r = 0; r < 4; ++r) {
                const int row = m0 + wm + mi * 16 + quad * 4 + r;
                const float vv = acc[mi][ni][r] + bb;
                size_t addr;
                if (MODE == 0) {
                    addr = (size_t)row * N + col;
                } else {
                    const int b = row / SEQ, s = row - b * SEQ;
                    const int h = col >> 6, df = col & 63;
                    if (MODE == 1)
                        addr = (((size_t)(b * NH + h)) * SEQ + s) * DF + df;
                    else
                        addr = (((size_t)(b * NH + h)) * DF + df) * SPAD + s;
                }
                C[addr] = (OutT)vv;
            }
        }
    }
}

// ---------------------------------------------------------------------------
// MFMA attention. One block per (b,h); 4 waves, each wave independently owns
// q-tiles {w, w+4, w+8, ...} of 13 (16-row) tiles covering S=200 (pad 208).
//
// K staged in LDS [208][72]  (pad -> 2-way bank aliasing only, free).
// V staged from Vt[b,h][DF][SPAD] into LDS [64][232], cols >=200 zeroed so
//   the padded PV reduction (K=224) never touches workspace garbage.
// P routed via a PER-WAVE LDS buffer [16][232] (bf16) to re-lay the score
//   D-layout (col=lane&15,row=quad*4+r) into the MFMA A-layout. Cols 208..223
//   zeroed once; cols 200..207 get exp(NEG-m)=0 from the k-bound mask.
// No __syncthreads in the main loop: waves fully independent.
// 1/l and zero_pad folded into the output store. Rows >=200 are computed on
// garbage but never stored (MFMA rows are independent).
// ---------------------------------------------------------------------------
#define KROWS 208
#define KSTR  72
#define VSTR  232
#define PSTR  232

__global__ __launch_bounds__(256, 1)
void attn_mfma(const __bf16* __restrict__ Qh,
               const __bf16* __restrict__ Kh,
               const __bf16* __restrict__ Vt,
               __bf16* __restrict__ Ctx,
               const int* __restrict__ zp)
{
    __shared__ __align__(16) __bf16 Kl[KROWS * KSTR];   // 29952 B
    __shared__ __align__(16) __bf16 Vl[DF * VSTR];      // 29696 B
    __shared__ __align__(16) __bf16 Pl[4][16 * PSTR];   // 29696 B

    const int tid  = threadIdx.x;
    const int w    = tid >> 6, lane = tid & 63;
    const int lr   = lane & 15, quad = lane >> 4;
    const int bh   = blockIdx.x;
    const int b    = bh >> 3, h = bh & 7;
    const size_t qkbase = (size_t)bh * SEQ * DF;
    const size_t vbase  = (size_t)bh * DF * SPAD;
    const int zero_pad = zp[0];

    // ---- stage K: 208 rows x 64 cols (rows >=200 are harmless garbage,
    //      masked at score time). Reads stay inside the workspace.
    for (int i = tid; i < (KROWS * DF) / 8; i += 256) {
        const int row = i >> 3, c8 = (i & 7) * 8;
        *(bf16x8*)&Kl[row * KSTR + c8] =
            *(const bf16x8*)(Kh + qkbase + (size_t)row * DF + c8);
    }
    // ---- stage V^T: 64 rows(d) x 224 cols(k); k>=200 zeroed.
    for (int i = tid; i < (DF * 224) / 8; i += 256) {
        const int d = i / 28, kb = (i % 28) * 8;
        bf16x8 vv = {};
        if (kb < SEQ)
            vv = *(const bf16x8*)(Vt + vbase + (size_t)d * SPAD + kb);
        *(bf16x8*)&Vl[d * VSTR + kb] = vv;
    }
    // ---- zero P pad cols 208..223 (once; never rewritten)
    if (tid < 128) {
        const int wv = tid >> 5, rr = (tid >> 1) & 15, cb8 = 208 + (tid & 1) * 8;
        *(bf16x8*)&Pl[wv][rr * PSTR + cb8] = (bf16x8){};
    }
    __syncthreads();

    __bf16* pw = Pl[w];

    for (int qt = w; qt < 13; qt += 4) {
        const int qrow0 = qt * 16 + quad * 4;

        // Q A-fragments straight from global (L1/L2-resident)
        bf16x8 qf0, qf1;
        {
            const __bf16* qp = Qh + qkbase + (size_t)(qt * 16 + lr) * DF + quad * 8;
            qf0 = *(const bf16x8*)qp;
            qf1 = *(const bf16x8*)(qp + 32);
        }

        // ---- scores S[16 q][208 k]
        f32x4 sc[13];
#pragma unroll
        for (int kt = 0; kt < 13; ++kt) {
            const int krow = kt * 16 + lr;
            const bf16x8 kf0 = *(const bf16x8*)&Kl[krow * KSTR + quad * 8];
            const bf16x8 kf1 = *(const bf16x8*)&Kl[krow * KSTR + 32 + quad * 8];
            f32x4 z = {};
            z = __builtin_amdgcn_mfma_f32_16x16x32_bf16(qf0, kf0, z, 0, 0, 0);
            z = __builtin_amdgcn_mfma_f32_16x16x32_bf16(qf1, kf1, z, 0, 0, 0);
            sc[kt] = z;
        }

        // ---- causal + bounds mask, row max
        float mx[4] = {NEG, NEG, NEG, NEG};
#pragma unroll
        for (int kt = 0; kt < 13; ++kt) {
            const int kcol = kt * 16 + lr;
#pragma unroll
            for (int r = 0; r < 4; ++r) {
                const int qq = qrow0 + r;
                const float s = (kcol <= qq && kcol < SEQ) ? sc[kt][r] * 0.125f : NEG;
                sc[kt][r] = s;
                mx[r] = fmaxf(mx[r], s);
            }
        }
#pragma unroll
        for (int o = 1; o < 16; o <<= 1) {
#pragma unroll
            for (int r = 0; r < 4; ++r)
                mx[r] = fmaxf(mx[r], __shfl_xor(mx[r], o, 64));
        }

        // ---- exp + row sum
        float sm[4] = {0.f, 0.f, 0.f, 0.f};
#pragma unroll
        for (int kt = 0; kt < 13; ++kt) {
#pragma unroll
            for (int r = 0; r < 4; ++r) {
                const float p = __expf(sc[kt][r] - mx[r]);
                sc[kt][r] = p;
                sm[r] += p;
            }
        }
#pragma unroll
        for (int o = 1; o < 16; o <<= 1) {
#pragma unroll
            for (int r = 0; r < 4; ++r)
                sm[r] += __shfl_xor(sm[r], o, 64);
        }

        // ---- P (bf16) -> per-wave LDS, re-laid for the PV A-operand
#pragma unroll
        for (int kt = 0; kt < 13; ++kt) {
#pragma unroll
            for (int r = 0; r < 4; ++r)
                pw[(quad * 4 + r) * PSTR + kt * 16 + lr] = (__bf16)sc[kt][r];
        }

        // ---- O[16 q][64 d] = P @ V   (K = 224, zero-padded)
        f32x4 oacc[4] = {};
#pragma unroll
        for (int kt2 = 0; kt2 < 7; ++kt2) {
            const bf16x8 pf =
                *(const bf16x8*)&pw[lr * PSTR + kt2 * 32 + quad * 8];
#pragma unroll
            for (int nt = 0; nt < 4; ++nt) {
                const bf16x8 vf =
                    *(const bf16x8*)&Vl[(nt * 16 + lr) * VSTR + kt2 * 32 + quad * 8];
                oacc[nt] = __builtin_amdgcn_mfma_f32_16x16x32_bf16(
                    pf, vf, oacc[nt], 0, 0, 0);
            }
        }

        // ---- store (fold 1/l and zero_pad)
        float il[4];
#pragma unroll
        for (int r = 0; r < 4; ++r) il[r] = 1.0f / sm[r];
#pragma unroll
        for (int nt = 0; nt < 4; ++nt) {
            const int d = nt * 16 + lr;
#pragma unroll
            for (int r = 0; r < 4; ++r) {
                const int qq = qrow0 + r;
                if (qq < SEQ) {
                    float ov = oacc[nt][r] * il[r];
                    if (zero_pad && qq == 0) ov = 0.0f;
                    Ctx[((size_t)(b * SEQ + qq)) * DIM + h * DF + d] = (__bf16)ov;
                }
            }
        }
    }
}

// ---------------------------------------------------------------------------
extern "C" void kernel_launch(void* const* d_in, const int* in_sizes, int n_in,
                              void* d_out, int out_size, void* d_ws, size_t ws_size,
                              hipStream_t stream)
{
    const void* q  = d_in[0];
    const void* k  = d_in[1];
    const void* v  = d_in[2];
    const void* Ws[4] = {d_in[3], d_in[5], d_in[7], d_in[9]};
    const void* bs[4] = {d_in[4], d_in[6], d_in[8], d_in[10]};
    const int*  zp = (const int*)d_in[12];
    float* Out = (float*)d_out;          // reference output dtype is FLOAT32

    // flags at ints [0..10]
    int* flags = (int*)d_ws;
    __bf16* Wc[4]; __bf16* bc[4];
    __bf16* p = (__bf16*)((char*)d_ws + 256);
    for (int i = 0; i < 4; ++i) { Wc[i] = p; p += (size_t)DIM * DIM; }
    for (int i = 0; i < 4; ++i) { bc[i] = p; p += DIM; }
    const size_t fixed_bytes = (size_t)((char*)p - (char*)d_ws);

    const int B_total = 128;
    int cb = 128;
    while (cb > 16) {
        const size_t crows_t = (size_t)cb * SEQ;
        const size_t elems = 3 * crows_t * DIM + (size_t)cb * NH * DF * SPAD;
        if (fixed_bytes + elems * 2 <= ws_size) break;
        cb >>= 1;
    }
    const int nchunk = B_total / cb;
    const size_t crows = (size_t)cb * SEQ;
    const size_t celems = crows * DIM;

    __bf16* Qh  = p;
    __bf16* Kh  = Qh + celems;
    __bf16* Vt  = Kh + celems;                       // [cb,H,DF,SPAD]
    __bf16* Ctx = Vt + (size_t)cb * NH * DF * SPAD;  // [crows, DIM]

    const dim3 blk(256);
    const dim3 g((unsigned)(crows / 128), DIM / 128);

    // per-tensor dtype detection (inputs may be bf16-ified by the harness)
    detect_kernel<<<1, 256, 0, stream>>>((const unsigned short*)q, &flags[0]);
    detect_kernel<<<1, 256, 0, stream>>>((const unsigned short*)k, &flags[1]);
    detect_kernel<<<1, 256, 0, stream>>>((const unsigned short*)v, &flags[2]);
    for (int i = 0; i < 4; ++i) {
        detect_kernel<<<1, 256, 0, stream>>>((const unsigned short*)Ws[i], &flags[3 + i]);
        detect_kernel<<<1, 256, 0, stream>>>((const unsigned short*)bs[i], &flags[7 + i]);
    }
    for (int i = 0; i < 4; ++i) {
        cvt_kernel<<<128, 256, 0, stream>>>(Ws[i], Wc[i], (long)DIM * DIM / 8, &flags[3 + i]);
        cvt_kernel<<<1, 64, 0, stream>>>(bs[i], bc[i], DIM / 8, &flags[7 + i]);
    }

    for (int c = 0; c < nchunk; ++c) {
        const long moff = (long)c * (long)crows;
        gemm_bt_kernel<1, 1, __bf16><<<g, blk, 0, stream>>>(
            q, moff, Wc[0], bc[0], Qh, (int)crows, DIM, DIM, &flags[0]);
        gemm_bt_kernel<1, 1, __bf16><<<g, blk, 0, stream>>>(
            k, moff, Wc[1], bc[1], Kh, (int)crows, DIM, DIM, &flags[1]);
        gemm_bt_kernel<2, 1, __bf16><<<g, blk, 0, stream>>>(
            v, moff, Wc[2], bc[2], Vt, (int)crows, DIM, DIM, &flags[2]);
        attn_mfma<<<dim3(cb * NH), blk, 0, stream>>>(Qh, Kh, Vt, Ctx, zp);
        gemm_bt_kernel<0, 0, float><<<g, blk, 0, stream>>>(
            Ctx, 0, Wc[3], bc[3], Out + (size_t)c * celems,
            (int)crows, DIM, DIM, nullptr);
    }
}

// Round 2
// 419.162 us; speedup vs baseline: 3.8177x; 1.3184x over previous
//
#include <hip/hip_runtime.h>
#include <hip/hip_bf16.h>

#define SEQ  200
#define DIM  512
#define NH   8
#define DF   64
#define SPAD 256
#define NEG  -1.0e30f

typedef __bf16 bf16x8 __attribute__((ext_vector_type(8)));
typedef __bf16 bf16x4 __attribute__((ext_vector_type(4)));
typedef float  f32x4  __attribute__((ext_vector_type(4)));

// async global->LDS, 16B per lane (dest must be wave-uniform base + lane*16)
__device__ __forceinline__ void async_lds16(const void* g, void* l)
{
    __builtin_amdgcn_global_load_lds(
        (const __attribute__((address_space(1))) void*)g,
        (__attribute__((address_space(3))) void*)l, 16, 0, 0);
}

// ---------------------------------------------------------------------------
// Per-tensor dtype detection (512 u16 words). flag=1 -> f32.
// ---------------------------------------------------------------------------
__global__ void detect_kernel(const unsigned short* __restrict__ src,
                              int* __restrict__ flag)
{
    __shared__ int cnt;
    if (threadIdx.x == 0) cnt = 0;
    __syncthreads();
    int ok = 0;
#pragma unroll
    for (int i = 0; i < 2; ++i) {
        const unsigned short u = src[threadIdx.x * 2 + i];
        const float f = __uint_as_float(((unsigned int)u) << 16);
        const float a = fabsf(f);
        ok += (f == 0.0f) || (a >= 6.0e-5f && a <= 64.0f);
    }
    atomicAdd(&cnt, ok);
    __syncthreads();
    if (threadIdx.x == 0) flag[0] = (cnt < 448) ? 1 : 0;
}

// ---------------------------------------------------------------------------
// Canonicalize a tensor to bf16 according to its own flag.
// ---------------------------------------------------------------------------
__global__ void cvt_kernel(const void* __restrict__ src,
                           __bf16* __restrict__ dst, long n8,
                           const int* __restrict__ flag)
{
    const int f32mode = flag[0];
    long i = (long)blockIdx.x * blockDim.x + threadIdx.x;
    const long stride = (long)gridDim.x * blockDim.x;
    if (f32mode) {
        const f32x4* s = (const f32x4*)src;
        for (; i < n8; i += stride) {
            const f32x4 a = s[2 * i], b = s[2 * i + 1];
            bf16x8 o;
            o[0] = (__bf16)a[0]; o[1] = (__bf16)a[1];
            o[2] = (__bf16)a[2]; o[3] = (__bf16)a[3];
            o[4] = (__bf16)b[0]; o[5] = (__bf16)b[1];
            o[6] = (__bf16)b[2]; o[7] = (__bf16)b[3];
            ((bf16x8*)dst)[i] = o;
        }
    } else {
        const bf16x8* s = (const bf16x8*)src;
        for (; i < n8; i += stride) ((bf16x8*)dst)[i] = s[i];
    }
}

// ---------------------------------------------------------------------------
// GEMM: C = A[m_off.., K] @ Bt[N,K]^T + bias[N]; fp32 accum.
// 2-phase pipelined: double-buffered LDS, ONE barrier per K-step, prefetch
// (global_load_lds for bf16 operands, reg-staged convert for f32 A) issued
// after the barrier and drained at the next barrier -> latency hides under
// the MFMA cluster.
// MODE 0: C row-major [M,N]; MODE 1: C->[b,H,S,DF]; MODE 2: C->[b,H,DF,SPAD]
//   (MODE 2 stores packed bf16x4 along s: zero write amplification).
// ---------------------------------------------------------------------------
template <int MODE, int USE_FLAG, typename OutT>
__global__ __launch_bounds__(256, 2)
void gemm_bt_kernel(const void* __restrict__ Araw, long m_off,
                    const __bf16* __restrict__ Bt,
                    const __bf16* __restrict__ bias,
                    OutT* __restrict__ C,
                    int M, int N, int K,
                    const int* __restrict__ flag)
{
    __shared__ __align__(16) __bf16 lA[2][128 * 32];
    __shared__ __align__(16) __bf16 lB[2][128 * 32];

    const int af32 = USE_FLAG ? flag[0] : 0;
    const __bf16* A16 = (const __bf16*)Araw;
    const float*  A32 = (const float*)Araw;

    const int tid  = threadIdx.x;
    const int m0   = blockIdx.x * 128;
    const int n0   = blockIdx.y * 128;
    const int w    = tid >> 6;
    const int lane = tid & 63;
    const int lr   = lane & 15, quad = lane >> 4;
    const int wm   = (w >> 1) * 64, wn = (w & 1) * 64;

    // staging coords: elem e = (p*256+tid)*8 ; row = e/32 ; col = e%32
    int srow[2], scol[2];
#pragma unroll
    for (int p = 0; p < 2; ++p) {
        const int e = (p * 256 + tid) * 8;
        srow[p] = e >> 5;
        scol[p] = e & 31;
    }

    const int KS = K >> 5;
    f32x4 rf[2][2];            // f32-A staging registers

    // ---- prologue: stage K-step 0 into buffer 0
#pragma unroll
    for (int p = 0; p < 2; ++p)
        async_lds16(Bt + (size_t)(n0 + srow[p]) * K + scol[p],
                    &lB[0][(p * 256 + tid) * 8]);
    if (af32) {
#pragma unroll
        for (int p = 0; p < 2; ++p) {
            const size_t aoff = (size_t)(m_off + m0 + srow[p]) * K + scol[p];
            rf[p][0] = *(const f32x4*)(A32 + aoff);
            rf[p][1] = *(const f32x4*)(A32 + aoff + 4);
        }
    } else {
#pragma unroll
        for (int p = 0; p < 2; ++p)
            async_lds16(A16 + (size_t)(m_off + m0 + srow[p]) * K + scol[p],
                        &lA[0][(p * 256 + tid) * 8]);
    }

    f32x4 acc[4][4] = {};

    for (int ks = 0; ks < KS; ++ks) {
        const int buf = ks & 1;

        if (af32) {
            // convert+store current A regs (writes lA[buf]; nobody reads it
            // before the barrier below)
#pragma unroll
            for (int p = 0; p < 2; ++p) {
                bf16x8 o;
                o[0] = (__bf16)rf[p][0][0]; o[1] = (__bf16)rf[p][0][1];
                o[2] = (__bf16)rf[p][0][2]; o[3] = (__bf16)rf[p][0][3];
                o[4] = (__bf16)rf[p][1][0]; o[5] = (__bf16)rf[p][1][1];
                o[6] = (__bf16)rf[p][1][2]; o[7] = (__bf16)rf[p][1][3];
                *(bf16x8*)&lA[buf][(p * 256 + tid) * 8] = o;
            }
        }

        // single barrier per K-step: drains the async loads for this step,
        // publishes ds-writes, and fences the previous step's LDS reads.
        __syncthreads();

        // ---- prefetch next K-step into the other buffer (drains at next
        //      barrier; overlaps the MFMA cluster below)
        if (ks + 1 < KS) {
            const int k1 = (ks + 1) * 32;
#pragma unroll
            for (int p = 0; p < 2; ++p)
                async_lds16(Bt + (size_t)(n0 + srow[p]) * K + k1 + scol[p],
                            &lB[buf ^ 1][(p * 256 + tid) * 8]);
            if (af32) {
#pragma unroll
                for (int p = 0; p < 2; ++p) {
                    const size_t aoff =
                        (size_t)(m_off + m0 + srow[p]) * K + k1 + scol[p];
                    rf[p][0] = *(const f32x4*)(A32 + aoff);
                    rf[p][1] = *(const f32x4*)(A32 + aoff + 4);
                }
            } else {
#pragma unroll
                for (int p = 0; p < 2; ++p)
                    async_lds16(A16 + (size_t)(m_off + m0 + srow[p]) * K + k1 + scol[p],
                                &lA[buf ^ 1][(p * 256 + tid) * 8]);
            }
        }

        // ---- compute current step
        bf16x8 af[4], bfr[4];
#pragma unroll
        for (int mi = 0; mi < 4; ++mi)
            af[mi] = *(const bf16x8*)&lA[buf][(wm + mi * 16 + lr) * 32 + quad * 8];
#pragma unroll
        for (int ni = 0; ni < 4; ++ni)
            bfr[ni] = *(const bf16x8*)&lB[buf][(wn + ni * 16 + lr) * 32 + quad * 8];
#pragma unroll
        for (int mi = 0; mi < 4; ++mi)
#pragma unroll
            for (int ni = 0; ni < 4; ++ni)
                acc[mi][ni] = __builtin_amdgcn_mfma_f32_16x16x32_bf16(
                    af[mi], bfr[ni], acc[mi][ni], 0, 0, 0);
    }

    // C/D layout: col=lane&15, row=quad*4+r  [diag1-verified on-device]
#pragma unroll
    for (int ni = 0; ni < 4; ++ni) {
        const int col = n0 + wn + ni * 16 + lr;
        const float bb = (float)bias[col];
        if constexpr (MODE == 2) {
            // packed store: acc[mi][ni][0..3] are 4 consecutive s for one df
            const int h = col >> 6, df = col & 63;
#pragma unroll
            for (int mi = 0; mi < 4; ++mi) {
                const int row0 = m0 + wm + mi * 16 + quad * 4;
                const int b = row0 / SEQ, s0 = row0 - b * SEQ;  // s0 mult of 4
                bf16x4 pk;
#pragma unroll
                for (int r = 0; r < 4; ++r)
                    pk[r] = (__bf16)(acc[mi][ni][r] + bb);
                *(bf16x4*)&C[(((size_t)(b * NH + h)) * DF + df) * SPAD + s0] = pk;
            }
        } else {
#pragma unroll
            for (int mi = 0; mi < 4; ++mi) {
#pragma unroll
                for (int r = 0; r < 4; ++r) {
                    const int row = m0 + wm + mi * 16 + quad * 4 + r;
                    const float vv = acc[mi][ni][r] + bb;
                    size_t addr;
                    if (MODE == 0) {
                        addr = (size_t)row * N + col;
                    } else {
                        const int b = row / SEQ, s = row - b * SEQ;
                        const int h = col >> 6, df = col & 63;
                        addr = (((size_t)(b * NH + h)) * SEQ + s) * DF + df;
                    }
                    C[addr] = (OutT)vv;
                }
            }
        }
    }
}

// ---------------------------------------------------------------------------
// MFMA attention (unchanged this round). One block per (b,h); 4 independent
// waves; K [208][72] + V^T [64][232] in LDS; P via per-wave LDS buffer.
// ---------------------------------------------------------------------------
#define KROWS 208
#define KSTR  72
#define VSTR  232
#define PSTR  232

__global__ __launch_bounds__(256, 1)
void attn_mfma(const __bf16* __restrict__ Qh,
               const __bf16* __restrict__ Kh,
               const __bf16* __restrict__ Vt,
               __bf16* __restrict__ Ctx,
               const int* __restrict__ zp)
{
    __shared__ __align__(16) __bf16 Kl[KROWS * KSTR];
    __shared__ __align__(16) __bf16 Vl[DF * VSTR];
    __shared__ __align__(16) __bf16 Pl[4][16 * PSTR];

    const int tid  = threadIdx.x;
    const int w    = tid >> 6, lane = tid & 63;
    const int lr   = lane & 15, quad = lane >> 4;
    const int bh   = blockIdx.x;
    const int b    = bh >> 3, h = bh & 7;
    const size_t qkbase = (size_t)bh * SEQ * DF;
    const size_t vbase  = (size_t)bh * DF * SPAD;
    const int zero_pad = zp[0];

    for (int i = tid; i < (KROWS * DF) / 8; i += 256) {
        const int row = i >> 3, c8 = (i & 7) * 8;
        *(bf16x8*)&Kl[row * KSTR + c8] =
            *(const bf16x8*)(Kh + qkbase + (size_t)row * DF + c8);
    }
    for (int i = tid; i < (DF * 224) / 8; i += 256) {
        const int d = i / 28, kb = (i % 28) * 8;
        bf16x8 vv = {};
        if (kb < SEQ)
            vv = *(const bf16x8*)(Vt + vbase + (size_t)d * SPAD + kb);
        *(bf16x8*)&Vl[d * VSTR + kb] = vv;
    }
    if (tid < 128) {
        const int wv = tid >> 5, rr = (tid >> 1) & 15, cb8 = 208 + (tid & 1) * 8;
        *(bf16x8*)&Pl[wv][rr * PSTR + cb8] = (bf16x8){};
    }
    __syncthreads();

    __bf16* pw = Pl[w];

    for (int qt = w; qt < 13; qt += 4) {
        const int qrow0 = qt * 16 + quad * 4;

        bf16x8 qf0, qf1;
        {
            const __bf16* qp = Qh + qkbase + (size_t)(qt * 16 + lr) * DF + quad * 8;
            qf0 = *(const bf16x8*)qp;
            qf1 = *(const bf16x8*)(qp + 32);
        }

        f32x4 sc[13];
#pragma unroll
        for (int kt = 0; kt < 13; ++kt) {
            const int krow = kt * 16 + lr;
            const bf16x8 kf0 = *(const bf16x8*)&Kl[krow * KSTR + quad * 8];
            const bf16x8 kf1 = *(const bf16x8*)&Kl[krow * KSTR + 32 + quad * 8];
            f32x4 z = {};
            z = __builtin_amdgcn_mfma_f32_16x16x32_bf16(qf0, kf0, z, 0, 0, 0);
            z = __builtin_amdgcn_mfma_f32_16x16x32_bf16(qf1, kf1, z, 0, 0, 0);
            sc[kt] = z;
        }

        float mx[4] = {NEG, NEG, NEG, NEG};
#pragma unroll
        for (int kt = 0; kt < 13; ++kt) {
            const int kcol = kt * 16 + lr;
#pragma unroll
            for (int r = 0; r < 4; ++r) {
                const int qq = qrow0 + r;
                const float s = (kcol <= qq && kcol < SEQ) ? sc[kt][r] * 0.125f : NEG;
                sc[kt][r] = s;
                mx[r] = fmaxf(mx[r], s);
            }
        }
#pragma unroll
        for (int o = 1; o < 16; o <<= 1) {
#pragma unroll
            for (int r = 0; r < 4; ++r)
                mx[r] = fmaxf(mx[r], __shfl_xor(mx[r], o, 64));
        }

        float sm[4] = {0.f, 0.f, 0.f, 0.f};
#pragma unroll
        for (int kt = 0; kt < 13; ++kt) {
#pragma unroll
            for (int r = 0; r < 4; ++r) {
                const float p = __expf(sc[kt][r] - mx[r]);
                sc[kt][r] = p;
                sm[r] += p;
            }
        }
#pragma unroll
        for (int o = 1; o < 16; o <<= 1) {
#pragma unroll
            for (int r = 0; r < 4; ++r)
                sm[r] += __shfl_xor(sm[r], o, 64);
        }

#pragma unroll
        for (int kt = 0; kt < 13; ++kt) {
#pragma unroll
            for (int r = 0; r < 4; ++r)
                pw[(quad * 4 + r) * PSTR + kt * 16 + lr] = (__bf16)sc[kt][r];
        }

        f32x4 oacc[4] = {};
#pragma unroll
        for (int kt2 = 0; kt2 < 7; ++kt2) {
            const bf16x8 pf =
                *(const bf16x8*)&pw[lr * PSTR + kt2 * 32 + quad * 8];
#pragma unroll
            for (int nt = 0; nt < 4; ++nt) {
                const bf16x8 vf =
                    *(const bf16x8*)&Vl[(nt * 16 + lr) * VSTR + kt2 * 32 + quad * 8];
                oacc[nt] = __builtin_amdgcn_mfma_f32_16x16x32_bf16(
                    pf, vf, oacc[nt], 0, 0, 0);
            }
        }

        float il[4];
#pragma unroll
        for (int r = 0; r < 4; ++r) il[r] = 1.0f / sm[r];
#pragma unroll
        for (int nt = 0; nt < 4; ++nt) {
            const int d = nt * 16 + lr;
#pragma unroll
            for (int r = 0; r < 4; ++r) {
                const int qq = qrow0 + r;
                if (qq < SEQ) {
                    float ov = oacc[nt][r] * il[r];
                    if (zero_pad && qq == 0) ov = 0.0f;
                    Ctx[((size_t)(b * SEQ + qq)) * DIM + h * DF + d] = (__bf16)ov;
                }
            }
        }
    }
}

// ---------------------------------------------------------------------------
extern "C" void kernel_launch(void* const* d_in, const int* in_sizes, int n_in,
                              void* d_out, int out_size, void* d_ws, size_t ws_size,
                              hipStream_t stream)
{
    const void* q  = d_in[0];
    const void* k  = d_in[1];
    const void* v  = d_in[2];
    const void* Ws[4] = {d_in[3], d_in[5], d_in[7], d_in[9]};
    const void* bs[4] = {d_in[4], d_in[6], d_in[8], d_in[10]};
    const int*  zp = (const int*)d_in[12];
    float* Out = (float*)d_out;          // reference output dtype is FLOAT32

    // flags at ints [0..10]
    int* flags = (int*)d_ws;
    __bf16* Wc[4]; __bf16* bc[4];
    __bf16* p = (__bf16*)((char*)d_ws + 256);
    for (int i = 0; i < 4; ++i) { Wc[i] = p; p += (size_t)DIM * DIM; }
    for (int i = 0; i < 4; ++i) { bc[i] = p; p += DIM; }
    const size_t fixed_bytes = (size_t)((char*)p - (char*)d_ws);

    const int B_total = 128;
    int cb = 128;
    while (cb > 16) {
        const size_t crows_t = (size_t)cb * SEQ;
        const size_t elems = 3 * crows_t * DIM + (size_t)cb * NH * DF * SPAD;
        if (fixed_bytes + elems * 2 <= ws_size) break;
        cb >>= 1;
    }
    const int nchunk = B_total / cb;
    const size_t crows = (size_t)cb * SEQ;
    const size_t celems = crows * DIM;

    __bf16* Qh  = p;
    __bf16* Kh  = Qh + celems;
    __bf16* Vt  = Kh + celems;                       // [cb,H,DF,SPAD]
    __bf16* Ctx = Vt + (size_t)cb * NH * DF * SPAD;  // [crows, DIM]

    const dim3 blk(256);
    const dim3 g((unsigned)(crows / 128), DIM / 128);

    // per-tensor dtype detection (inputs may be bf16-ified by the harness)
    detect_kernel<<<1, 256, 0, stream>>>((const unsigned short*)q, &flags[0]);
    detect_kernel<<<1, 256, 0, stream>>>((const unsigned short*)k, &flags[1]);
    detect_kernel<<<1, 256, 0, stream>>>((const unsigned short*)v, &flags[2]);
    for (int i = 0; i < 4; ++i) {
        detect_kernel<<<1, 256, 0, stream>>>((const unsigned short*)Ws[i], &flags[3 + i]);
        detect_kernel<<<1, 256, 0, stream>>>((const unsigned short*)bs[i], &flags[7 + i]);
    }
    for (int i = 0; i < 4; ++i) {
        cvt_kernel<<<128, 256, 0, stream>>>(Ws[i], Wc[i], (long)DIM * DIM / 8, &flags[3 + i]);
        cvt_kernel<<<1, 64, 0, stream>>>(bs[i], bc[i], DIM / 8, &flags[7 + i]);
    }

    for (int c = 0; c < nchunk; ++c) {
        const long moff = (long)c * (long)crows;
        gemm_bt_kernel<1, 1, __bf16><<<g, blk, 0, stream>>>(
            q, moff, Wc[0], bc[0], Qh, (int)crows, DIM, DIM, &flags[0]);
        gemm_bt_kernel<1, 1, __bf16><<<g, blk, 0, stream>>>(
            k, moff, Wc[1], bc[1], Kh, (int)crows, DIM, DIM, &flags[1]);
        gemm_bt_kernel<2, 1, __bf16><<<g, blk, 0, stream>>>(
            v, moff, Wc[2], bc[2], Vt, (int)crows, DIM, DIM, &flags[2]);
        attn_mfma<<<dim3(cb * NH), blk, 0, stream>>>(Qh, Kh, Vt, Ctx, zp);
        gemm_bt_kernel<0, 0, float><<<g, blk, 0, stream>>>(
            Ctx, 0, Wc[3], bc[3], Out + (size_t)c * celems,
            (int)crows, DIM, DIM, nullptr);
    }
}

// Round 4
// 329.658 us; speedup vs baseline: 4.8542x; 1.2715x over previous
//
#include <hip/hip_runtime.h>
#include <hip/hip_bf16.h>

#define SEQ  200
#define DIM  512
#define NH   8
#define DF   64
#define SPAD 256
#define NEG  -1.0e30f

typedef __bf16 bf16x8 __attribute__((ext_vector_type(8)));
typedef __bf16 bf16x4 __attribute__((ext_vector_type(4)));
typedef float  f32x4  __attribute__((ext_vector_type(4)));

// async global->LDS, 16B per lane (dest must be wave-uniform base + lane*16)
__device__ __forceinline__ void async_lds16(const void* g, void* l)
{
    __builtin_amdgcn_global_load_lds(
        (const __attribute__((address_space(1))) void*)g,
        (__attribute__((address_space(3))) void*)l, 16, 0, 0);
}

// ---------------------------------------------------------------------------
// Fused per-tensor dtype detection: block i handles tensor i. flag=1 -> f32.
// ---------------------------------------------------------------------------
struct DetArgs { const unsigned short* p[11]; };

__global__ void detect_all(DetArgs a, int* __restrict__ flags)
{
    const unsigned short* __restrict__ src = a.p[blockIdx.x];
    __shared__ int cnt;
    if (threadIdx.x == 0) cnt = 0;
    __syncthreads();
    int ok = 0;
#pragma unroll
    for (int i = 0; i < 2; ++i) {
        const unsigned short u = src[threadIdx.x * 2 + i];
        const float f = __uint_as_float(((unsigned int)u) << 16);
        const float fa = fabsf(f);
        ok += (f == 0.0f) || (fa >= 6.0e-5f && fa <= 64.0f);
    }
    atomicAdd(&cnt, ok);
    __syncthreads();
    if (threadIdx.x == 0) flags[blockIdx.x] = (cnt < 448) ? 1 : 0;
}

// ---------------------------------------------------------------------------
// Fused canonicalization: jobs 0..3 = weights (128 blocks each), 4..7 = biases
// (1 block each). flag index = 3 + job for both ranges.
// ---------------------------------------------------------------------------
struct CvtArgs { const void* src[8]; __bf16* dst[8]; };

__global__ void cvt_all(CvtArgs a, const int* __restrict__ flags)
{
    const int blk = blockIdx.x;
    int job; long idx, n8;
    if (blk < 512) { job = blk >> 7; idx = (long)(blk & 127) * 256 + threadIdx.x; n8 = (long)DIM * DIM / 8; }
    else           { job = 4 + (blk - 512); idx = threadIdx.x; n8 = DIM / 8; }
    if (idx >= n8) return;
    const int fl = flags[3 + job];
    if (fl) {
        const f32x4* s = (const f32x4*)a.src[job];
        const f32x4 x = s[2 * idx], y = s[2 * idx + 1];
        bf16x8 o;
        o[0] = (__bf16)x[0]; o[1] = (__bf16)x[1];
        o[2] = (__bf16)x[2]; o[3] = (__bf16)x[3];
        o[4] = (__bf16)y[0]; o[5] = (__bf16)y[1];
        o[6] = (__bf16)y[2]; o[7] = (__bf16)y[3];
        ((bf16x8*)a.dst[job])[idx] = o;
    } else {
        ((bf16x8*)a.dst[job])[idx] = ((const bf16x8*)a.src[job])[idx];
    }
}

// ---------------------------------------------------------------------------
// GEMM: C = A[m_off.., K] @ Bt[N,K]^T + bias[N]; fp32 accum.
// 2-phase pipelined: double-buffered LDS, ONE barrier per K-step, async
// prefetch overlapping the MFMA cluster.
// MODE 0: C row-major [M,N]; MODE 1: C->[b,H,S,DF]; MODE 2: C->[b,H,DF,SPAD]
//   (MODE 2 stores packed bf16x4 along s: zero write amplification).
// ---------------------------------------------------------------------------
template <int MODE, int USE_FLAG, typename OutT>
__global__ __launch_bounds__(256, 2)
void gemm_bt_kernel(const void* __restrict__ Araw, long m_off,
                    const __bf16* __restrict__ Bt,
                    const __bf16* __restrict__ bias,
                    OutT* __restrict__ C,
                    int M, int N, int K,
                    const int* __restrict__ flag)
{
    __shared__ __align__(16) __bf16 lA[2][128 * 32];
    __shared__ __align__(16) __bf16 lB[2][128 * 32];

    const int af32 = USE_FLAG ? flag[0] : 0;
    const __bf16* A16 = (const __bf16*)Araw;
    const float*  A32 = (const float*)Araw;

    const int tid  = threadIdx.x;
    const int m0   = blockIdx.x * 128;
    const int n0   = blockIdx.y * 128;
    const int w    = tid >> 6;
    const int lane = tid & 63;
    const int lr   = lane & 15, quad = lane >> 4;
    const int wm   = (w >> 1) * 64, wn = (w & 1) * 64;

    int srow[2], scol[2];
#pragma unroll
    for (int p = 0; p < 2; ++p) {
        const int e = (p * 256 + tid) * 8;
        srow[p] = e >> 5;
        scol[p] = e & 31;
    }

    const int KS = K >> 5;
    f32x4 rf[2][2];

#pragma unroll
    for (int p = 0; p < 2; ++p)
        async_lds16(Bt + (size_t)(n0 + srow[p]) * K + scol[p],
                    &lB[0][(p * 256 + tid) * 8]);
    if (af32) {
#pragma unroll
        for (int p = 0; p < 2; ++p) {
            const size_t aoff = (size_t)(m_off + m0 + srow[p]) * K + scol[p];
            rf[p][0] = *(const f32x4*)(A32 + aoff);
            rf[p][1] = *(const f32x4*)(A32 + aoff + 4);
        }
    } else {
#pragma unroll
        for (int p = 0; p < 2; ++p)
            async_lds16(A16 + (size_t)(m_off + m0 + srow[p]) * K + scol[p],
                        &lA[0][(p * 256 + tid) * 8]);
    }

    f32x4 acc[4][4] = {};

    for (int ks = 0; ks < KS; ++ks) {
        const int buf = ks & 1;

        if (af32) {
#pragma unroll
            for (int p = 0; p < 2; ++p) {
                bf16x8 o;
                o[0] = (__bf16)rf[p][0][0]; o[1] = (__bf16)rf[p][0][1];
                o[2] = (__bf16)rf[p][0][2]; o[3] = (__bf16)rf[p][0][3];
                o[4] = (__bf16)rf[p][1][0]; o[5] = (__bf16)rf[p][1][1];
                o[6] = (__bf16)rf[p][1][2]; o[7] = (__bf16)rf[p][1][3];
                *(bf16x8*)&lA[buf][(p * 256 + tid) * 8] = o;
            }
        }

        __syncthreads();

        if (ks + 1 < KS) {
            const int k1 = (ks + 1) * 32;
#pragma unroll
            for (int p = 0; p < 2; ++p)
                async_lds16(Bt + (size_t)(n0 + srow[p]) * K + k1 + scol[p],
                            &lB[buf ^ 1][(p * 256 + tid) * 8]);
            if (af32) {
#pragma unroll
                for (int p = 0; p < 2; ++p) {
                    const size_t aoff =
                        (size_t)(m_off + m0 + srow[p]) * K + k1 + scol[p];
                    rf[p][0] = *(const f32x4*)(A32 + aoff);
                    rf[p][1] = *(const f32x4*)(A32 + aoff + 4);
                }
            } else {
#pragma unroll
                for (int p = 0; p < 2; ++p)
                    async_lds16(A16 + (size_t)(m_off + m0 + srow[p]) * K + k1 + scol[p],
                                &lA[buf ^ 1][(p * 256 + tid) * 8]);
            }
        }

        bf16x8 af[4], bfr[4];
#pragma unroll
        for (int mi = 0; mi < 4; ++mi)
            af[mi] = *(const bf16x8*)&lA[buf][(wm + mi * 16 + lr) * 32 + quad * 8];
#pragma unroll
        for (int ni = 0; ni < 4; ++ni)
            bfr[ni] = *(const bf16x8*)&lB[buf][(wn + ni * 16 + lr) * 32 + quad * 8];
#pragma unroll
        for (int mi = 0; mi < 4; ++mi)
#pragma unroll
            for (int ni = 0; ni < 4; ++ni)
                acc[mi][ni] = __builtin_amdgcn_mfma_f32_16x16x32_bf16(
                    af[mi], bfr[ni], acc[mi][ni], 0, 0, 0);
    }

    // C/D layout: col=lane&15, row=quad*4+r  [diag1-verified on-device]
#pragma unroll
    for (int ni = 0; ni < 4; ++ni) {
        const int col = n0 + wn + ni * 16 + lr;
        const float bb = (float)bias[col];
        if constexpr (MODE == 2) {
            const int h = col >> 6, df = col & 63;
#pragma unroll
            for (int mi = 0; mi < 4; ++mi) {
                const int row0 = m0 + wm + mi * 16 + quad * 4;
                const int b = row0 / SEQ, s0 = row0 - b * SEQ;
                bf16x4 pk;
#pragma unroll
                for (int r = 0; r < 4; ++r)
                    pk[r] = (__bf16)(acc[mi][ni][r] + bb);
                *(bf16x4*)&C[(((size_t)(b * NH + h)) * DF + df) * SPAD + s0] = pk;
            }
        } else {
#pragma unroll
            for (int mi = 0; mi < 4; ++mi) {
#pragma unroll
                for (int r = 0; r < 4; ++r) {
                    const int row = m0 + wm + mi * 16 + quad * 4 + r;
                    const float vv = acc[mi][ni][r] + bb;
                    size_t addr;
                    if (MODE == 0) {
                        addr = (size_t)row * N + col;
                    } else {
                        const int b = row / SEQ, s = row - b * SEQ;
                        const int h = col >> 6, df = col & 63;
                        addr = (((size_t)(b * NH + h)) * SEQ + s) * DF + df;
                    }
                    C[addr] = (OutT)vv;
                }
            }
        }
    }
}

// ---------------------------------------------------------------------------
// MFMA attention, swapped-QK version. One block per (b,h); 4 independent
// waves; causal tile skipping with balanced wave->tile assignment.
//
// Swapped QK^T: mfma(A=K, B=Q) -> D[k][q]; lane holds q = lane&15 (fixed!),
//   k = kt*16 + quad*4 + r. Softmax = in-lane reduce + 2 shfl_xor (16,32).
//   P rows are lane-contiguous along k -> packed bf16x4 ds_writes.
// P buffer: per-wave [16 q][136 k] half-buffer; PV split into k-halves
//   (tiles 0..7, then 8..13). Zero tile written at kt = qt+1 covers both the
//   odd-tile and the k>=200 pad (V LDS also zeroed there).
// LDS 77056 B -> 2 blocks/CU.
// ---------------------------------------------------------------------------
#define KROWS 208
#define KSTR  72
#define VSTR  232
#define PSTR  136

__global__ __launch_bounds__(256, 2)
void attn_mfma(const __bf16* __restrict__ Qh,
               const __bf16* __restrict__ Kh,
               const __bf16* __restrict__ Vt,
               __bf16* __restrict__ Ctx,
               const int* __restrict__ zp)
{
    __shared__ __align__(16) __bf16 Kl[KROWS * KSTR];   // 29952 B
    __shared__ __align__(16) __bf16 Vl[DF * VSTR];      // 29696 B
    __shared__ __align__(16) __bf16 Pl[4][16 * PSTR];   // 17408 B

    const int tid  = threadIdx.x;
    const int w    = tid >> 6, lane = tid & 63;
    const int lr   = lane & 15, quad = lane >> 4;
    const int bh   = blockIdx.x;
    const int b    = bh >> 3, h = bh & 7;
    const size_t qkbase = (size_t)bh * SEQ * DF;
    const size_t vbase  = (size_t)bh * DF * SPAD;
    const int zero_pad = zp[0];

    for (int i = tid; i < (KROWS * DF) / 8; i += 256) {
        const int row = i >> 3, c8 = (i & 7) * 8;
        *(bf16x8*)&Kl[row * KSTR + c8] =
            *(const bf16x8*)(Kh + qkbase + (size_t)row * DF + c8);
    }
    for (int i = tid; i < (DF * 224) / 8; i += 256) {
        const int d = i / 28, kb = (i % 28) * 8;
        bf16x8 vv = {};
        if (kb < SEQ)
            vv = *(const bf16x8*)(Vt + vbase + (size_t)d * SPAD + kb);
        *(bf16x8*)&Vl[d * VSTR + kb] = vv;
    }
    __syncthreads();

    __bf16* pw = Pl[w];

    // balanced causal assignment (cost qt+1): w0{12,6,2} w1{11,7,1}
    // w2{10,8,3} w3{9,5,4,0}; nibble 0xF = sentinel
    const unsigned int mine =
        (unsigned int)(0x0459F38AF17BF26CULL >> (16 * w)) & 0xFFFFu;

    for (int j = 0; j < 4; ++j) {
        const int qt = (mine >> (4 * j)) & 15;
        if (qt == 15) continue;
        const int q = qt * 16 + lr;          // this lane's query row

        bf16x8 qf0, qf1;
        {
            const __bf16* qp = Qh + qkbase + (size_t)(qt * 16 + lr) * DF + quad * 8;
            qf0 = *(const bf16x8*)qp;
            qf1 = *(const bf16x8*)(qp + 32);
        }

        // ---- swapped QK^T (causal skip: kt <= qt)
        f32x4 sc[14];
#pragma unroll
        for (int kt = 0; kt < 13; ++kt) {
            if (kt > qt) continue;
            const int krow = kt * 16 + lr;
            const bf16x8 kf0 = *(const bf16x8*)&Kl[krow * KSTR + quad * 8];
            const bf16x8 kf1 = *(const bf16x8*)&Kl[krow * KSTR + 32 + quad * 8];
            f32x4 z = {};
            z = __builtin_amdgcn_mfma_f32_16x16x32_bf16(kf0, qf0, z, 0, 0, 0);
            z = __builtin_amdgcn_mfma_f32_16x16x32_bf16(kf1, qf1, z, 0, 0, 0);
            sc[kt] = z;
        }

        // ---- mask + in-lane max + 2-shfl reduce
        float mx = NEG;
#pragma unroll
        for (int kt = 0; kt < 13; ++kt) {
            if (kt > qt) continue;
#pragma unroll
            for (int r = 0; r < 4; ++r) {
                const int kk = kt * 16 + quad * 4 + r;
                const float s = (kk <= q && kk < SEQ) ? sc[kt][r] * 0.125f : NEG;
                sc[kt][r] = s;
                mx = fmaxf(mx, s);
            }
        }
        mx = fmaxf(mx, __shfl_xor(mx, 16, 64));
        mx = fmaxf(mx, __shfl_xor(mx, 32, 64));

        // ---- exp + in-lane sum + 2-shfl reduce
        float l = 0.0f;
#pragma unroll
        for (int kt = 0; kt < 13; ++kt) {
            if (kt > qt) continue;
#pragma unroll
            for (int r = 0; r < 4; ++r) {
                const float pv = __expf(sc[kt][r] - mx);
                sc[kt][r] = pv;
                l += pv;
            }
        }
        l += __shfl_xor(l, 16, 64);
        l += __shfl_xor(l, 32, 64);
        const float linv = 1.0f / l;

        f32x4 oacc[4] = {};

        // ---- half A: P tiles 0..7 (packed b64 writes), PV chunks 0..3
#pragma unroll
        for (int kt = 0; kt < 8; ++kt) {
            if (kt <= qt) {
                bf16x4 pkv;
#pragma unroll
                for (int r = 0; r < 4; ++r) pkv[r] = (__bf16)sc[kt][r];
                *(bf16x4*)&pw[lr * PSTR + kt * 16 + quad * 4] = pkv;
            } else if (kt == qt + 1) {
                *(bf16x4*)&pw[lr * PSTR + kt * 16 + quad * 4] = (bf16x4){};
            }
        }
#pragma unroll
        for (int c = 0; c < 4; ++c) {
            if (2 * c > qt) continue;
            const bf16x8 pf = *(const bf16x8*)&pw[lr * PSTR + c * 32 + quad * 8];
#pragma unroll
            for (int nt = 0; nt < 4; ++nt) {
                const bf16x8 vf =
                    *(const bf16x8*)&Vl[(nt * 16 + lr) * VSTR + c * 32 + quad * 8];
                oacc[nt] = __builtin_amdgcn_mfma_f32_16x16x32_bf16(
                    pf, vf, oacc[nt], 0, 0, 0);
            }
        }

        // ---- half B: P tiles 8..13 -> cols (kt-8)*16, PV chunks 4..6
        if (qt >= 8) {
#pragma unroll
            for (int kt = 8; kt < 14; ++kt) {
                if (kt <= qt) {
                    bf16x4 pkv;
#pragma unroll
                    for (int r = 0; r < 4; ++r) pkv[r] = (__bf16)sc[kt][r];
                    *(bf16x4*)&pw[lr * PSTR + (kt - 8) * 16 + quad * 4] = pkv;
                } else if (kt == qt + 1) {
                    *(bf16x4*)&pw[lr * PSTR + (kt - 8) * 16 + quad * 4] = (bf16x4){};
                }
            }
#pragma unroll
            for (int c = 0; c < 3; ++c) {
                if (2 * (c + 4) > qt) continue;
                const bf16x8 pf = *(const bf16x8*)&pw[lr * PSTR + c * 32 + quad * 8];
#pragma unroll
                for (int nt = 0; nt < 4; ++nt) {
                    const bf16x8 vf =
                        *(const bf16x8*)&Vl[(nt * 16 + lr) * VSTR + (c + 4) * 32 + quad * 8];
                    oacc[nt] = __builtin_amdgcn_mfma_f32_16x16x32_bf16(
                        pf, vf, oacc[nt], 0, 0, 0);
                }
            }
        }

        // ---- store: D[q][d] with q=quad*4+r, d=nt*16+lr; 1/l via lane shfl
        float il[4];
#pragma unroll
        for (int r = 0; r < 4; ++r) il[r] = __shfl(linv, quad * 4 + r, 16);
#pragma unroll
        for (int nt = 0; nt < 4; ++nt) {
            const int d = nt * 16 + lr;
#pragma unroll
            for (int r = 0; r < 4; ++r) {
                const int qq = qt * 16 + quad * 4 + r;
                if (qq < SEQ) {
                    float ov = oacc[nt][r] * il[r];
                    if (zero_pad && qq == 0) ov = 0.0f;
                    Ctx[((size_t)(b * SEQ + qq)) * DIM + h * DF + d] = (__bf16)ov;
                }
            }
        }
    }
}

// ---------------------------------------------------------------------------
extern "C" void kernel_launch(void* const* d_in, const int* in_sizes, int n_in,
                              void* d_out, int out_size, void* d_ws, size_t ws_size,
                              hipStream_t stream)
{
    const void* q  = d_in[0];
    const void* k  = d_in[1];
    const void* v  = d_in[2];
    const void* Ws[4] = {d_in[3], d_in[5], d_in[7], d_in[9]};
    const void* bs[4] = {d_in[4], d_in[6], d_in[8], d_in[10]};
    const int*  zp = (const int*)d_in[12];
    float* Out = (float*)d_out;          // reference output dtype is FLOAT32

    // flags at ints [0..10]
    int* flags = (int*)d_ws;
    __bf16* Wc[4]; __bf16* bc[4];
    __bf16* p = (__bf16*)((char*)d_ws + 256);
    for (int i = 0; i < 4; ++i) { Wc[i] = p; p += (size_t)DIM * DIM; }
    for (int i = 0; i < 4; ++i) { bc[i] = p; p += DIM; }
    const size_t fixed_bytes = (size_t)((char*)p - (char*)d_ws);

    const int B_total = 128;
    int cb = 128;
    while (cb > 16) {
        const size_t crows_t = (size_t)cb * SEQ;
        const size_t elems = 4 * crows_t * DIM + (size_t)cb * NH * DF * SPAD;
        if (fixed_bytes + elems * 2 <= ws_size) break;
        cb >>= 1;
    }
    const int nchunk = B_total / cb;
    const size_t crows = (size_t)cb * SEQ;
    const size_t celems = crows * DIM;

    __bf16* Qh  = p;
    __bf16* Kh  = Qh + celems;
    __bf16* Vt  = Kh + celems;                       // [cb,H,DF,SPAD]
    __bf16* Ctx = Vt + (size_t)cb * NH * DF * SPAD;  // [crows, DIM]

    const dim3 blk(256);
    const dim3 g((unsigned)(crows / 128), DIM / 128);

    // fused dtype detection + weight/bias canonicalization (2 launches)
    DetArgs da;
    da.p[0] = (const unsigned short*)q;
    da.p[1] = (const unsigned short*)k;
    da.p[2] = (const unsigned short*)v;
    for (int i = 0; i < 4; ++i) {
        da.p[3 + i] = (const unsigned short*)Ws[i];
        da.p[7 + i] = (const unsigned short*)bs[i];
    }
    detect_all<<<dim3(11), blk, 0, stream>>>(da, flags);

    CvtArgs ca;
    for (int i = 0; i < 4; ++i) {
        ca.src[i] = Ws[i];     ca.dst[i] = Wc[i];
        ca.src[4 + i] = bs[i]; ca.dst[4 + i] = bc[i];
    }
    cvt_all<<<dim3(516), blk, 0, stream>>>(ca, flags);

    for (int c = 0; c < nchunk; ++c) {
        const long moff = (long)c * (long)crows;
        gemm_bt_kernel<1, 1, __bf16><<<g, blk, 0, stream>>>(
            q, moff, Wc[0], bc[0], Qh, (int)crows, DIM, DIM, &flags[0]);
        gemm_bt_kernel<1, 1, __bf16><<<g, blk, 0, stream>>>(
            k, moff, Wc[1], bc[1], Kh, (int)crows, DIM, DIM, &flags[1]);
        gemm_bt_kernel<2, 1, __bf16><<<g, blk, 0, stream>>>(
            v, moff, Wc[2], bc[2], Vt, (int)crows, DIM, DIM, &flags[2]);
        attn_mfma<<<dim3(cb * NH), blk, 0, stream>>>(Qh, Kh, Vt, Ctx, zp);
        gemm_bt_kernel<0, 0, float><<<g, blk, 0, stream>>>(
            Ctx, 0, Wc[3], bc[3], Out + (size_t)c * celems,
            (int)crows, DIM, DIM, nullptr);
    }
}